// Round 3
// baseline (19204.991 us; speedup 1.0000x reference)
//
#include <hip/hip_runtime.h>
#include <hip/hip_bf16.h>
#include <hip/hip_cooperative_groups.h>

namespace cg = cooperative_groups;

// LSTM + dot-attention recurrence, B=64, S=512, D_IN=D_HID=1024, STEPS=64.
// Round 2: persistent cooperative kernel with LDS union kept < 64 KB so the
// cooperative-launch occupancy validation passes (round-1 failure diagnosis:
// 69.7 KB static LDS -> occupancy computed as 0 -> launch rejected).
// Fallback: if hipLaunchCooperativeKernel returns an error, launch the same
// six phases as discrete kernels (known-correct round-0 structure).

#define STEPS 64

struct Params {
  const float *hx, *cx, *ctx, *mask, *Wh, *bh, *Win, *Wout;
  float *out;
  float *h, *c, *hy, *gatesP, *inpP, *inpR, *pm, *pl, *pw, *outP;
};

union __align__(16) Smem {
  struct { float As[64][20]; float Bs[64][20]; } g;                   // 10.0 KB
  struct { float inp[1024]; float ctx[8][1024]; float sc[8]; } a;     // 36.9 KB
  struct { float A[64][132]; float Bs[64][20]; float wc[64][4]; } o;  // 39.9 KB
};

__device__ __forceinline__ float sigmf(float x) { return 1.f / (1.f + __expf(-x)); }

// C_part[64, n0:n0+64] = A[64, kbeg:kend] @ Bm[n0:n0+64, kbeg:kend]^T
__device__ void gemm_g(const float* __restrict__ A, int lda,
                       const float* __restrict__ Bm, int ldb,
                       float* __restrict__ Cp, int N, int n0,
                       int kbeg, int kend, Smem& s) {
  const int tid = threadIdx.x;
  const int tx = tid & 15, ty = tid >> 4;
  float acc[4][4] = {};
  for (int k0 = kbeg; k0 < kend; k0 += 16) {
    __syncthreads();
#pragma unroll
    for (int q = 0; q < 4; ++q) {
      s.g.As[q * 16 + ty][tx] = A[(size_t)(q * 16 + ty) * lda + k0 + tx];
      s.g.Bs[q * 16 + ty][tx] = Bm[(size_t)(n0 + q * 16 + ty) * ldb + k0 + tx];
    }
    __syncthreads();
#pragma unroll
    for (int kk = 0; kk < 16; kk += 4) {
      float4 av[4], bv[4];
#pragma unroll
      for (int i = 0; i < 4; ++i) av[i] = *(const float4*)&s.g.As[ty * 4 + i][kk];
#pragma unroll
      for (int j = 0; j < 4; ++j) bv[j] = *(const float4*)&s.g.Bs[tx * 4 + j][kk];
#pragma unroll
      for (int i = 0; i < 4; ++i)
#pragma unroll
        for (int j = 0; j < 4; ++j)
          acc[i][j] += av[i].x * bv[j].x + av[i].y * bv[j].y +
                       av[i].z * bv[j].z + av[i].w * bv[j].w;
    }
  }
#pragma unroll
  for (int i = 0; i < 4; ++i)
#pragma unroll
    for (int j = 0; j < 4; ++j)
      Cp[(size_t)(ty * 4 + i) * N + n0 + tx * 4 + j] = acc[i][j];
}

// C_part[64, n0:n0+64] = s.o.A[64, 0:128] @ Bm[n0:n0+64, kg:kg+128]^T
__device__ void gemm_o(const float* __restrict__ Bm, int ldb, int kgbeg,
                       float* __restrict__ Cp, int N, int n0, Smem& s) {
  const int tid = threadIdx.x;
  const int tx = tid & 15, ty = tid >> 4;
  float acc[4][4] = {};
  for (int k0 = 0; k0 < 128; k0 += 16) {
    __syncthreads();
#pragma unroll
    for (int q = 0; q < 4; ++q)
      s.o.Bs[q * 16 + ty][tx] = Bm[(size_t)(n0 + q * 16 + ty) * ldb + kgbeg + k0 + tx];
    __syncthreads();
#pragma unroll
    for (int kk = 0; kk < 16; kk += 4) {
      float4 av[4], bv[4];
#pragma unroll
      for (int i = 0; i < 4; ++i) av[i] = *(const float4*)&s.o.A[ty * 4 + i][k0 + kk];
#pragma unroll
      for (int j = 0; j < 4; ++j) bv[j] = *(const float4*)&s.o.Bs[tx * 4 + j][kk];
#pragma unroll
      for (int i = 0; i < 4; ++i)
#pragma unroll
        for (int j = 0; j < 4; ++j)
          acc[i][j] += av[i].x * bv[j].x + av[i].y * bv[j].y +
                       av[i].z * bv[j].z + av[i].w * bv[j].w;
    }
  }
#pragma unroll
  for (int i = 0; i < 4; ++i)
#pragma unroll
    for (int j = 0; j < 4; ++j)
      Cp[(size_t)(ty * 4 + i) * N + n0 + tx * 4 + j] = acc[i][j];
}

__device__ void phase0(const Params& p, int bid, int tid) {
  int idx = bid * 256 + tid;
  p.h[idx] = p.hx[idx];
  p.c[idx] = p.cx[idx];
}

__device__ void phase1(const Params& p, int bid, int tid, Smem& s) {
  int nt = bid >> 2, kc = bid & 3;
  gemm_g(p.h, 1024, p.Wh, 1024, p.gatesP + (size_t)kc * 262144, 4096,
         nt * 64, kc * 256, kc * 256 + 256, s);
}

__device__ void phase2(const Params& p, int bid, int tid) {
  int idx = bid * 256 + tid;
  int b = idx >> 10, j = idx & 1023;
  float gi = p.bh[j], gf = p.bh[1024 + j], gg = p.bh[2048 + j], go = p.bh[3072 + j];
#pragma unroll
  for (int q = 0; q < 4; ++q) {
    const float* gp = p.gatesP + (size_t)q * 262144 + (size_t)b * 4096;
    gi += gp[j]; gf += gp[1024 + j]; gg += gp[2048 + j]; go += gp[3072 + j];
  }
  float cy = sigmf(gf) * p.c[idx] + sigmf(gi) * tanhf(gg);
  p.c[idx] = cy;
  p.hy[idx] = sigmf(go) * tanhf(cy);
}

__device__ void phase3(const Params& p, int bid, int tid, Smem& s) {
  int nt = bid >> 4, kc = bid & 15;
  gemm_g(p.hy, 1024, p.Win, 1024, p.inpP + (size_t)kc * 65536, 1024,
         nt * 64, kc * 64, kc * 64 + 64, s);
}

__device__ void phase4(const Params& p, int bid, int tid, Smem& s) {
  const int b = bid >> 2, ch = bid & 3;
  const int lane = tid & 63, w = tid >> 6;
  for (int i = tid; i < 1024; i += 256) {
    float v = 0.f;
#pragma unroll
    for (int q = 0; q < 16; ++q) v += p.inpP[(size_t)q * 65536 + (size_t)b * 1024 + i];
    s.a.inp[i] = v;
    if (ch == 0) p.inpR[(size_t)b * 1024 + i] = v;
  }
  __syncthreads();
  float inpr[16];
#pragma unroll
  for (int i = 0; i < 16; ++i) inpr[i] = s.a.inp[lane + 64 * i];

  float m = -1e30f, l = 0.f;
  float pwv[4] = {0.f, 0.f, 0.f, 0.f};
  const float4* base = (const float4*)(p.ctx + (size_t)b * 524288 + (size_t)ch * 131072);
  for (int st = 0; st < 16; ++st) {
    __syncthreads();
    const float4* src = base + (size_t)st * 2048;
    float4* dst = (float4*)s.a.ctx;
    for (int i = tid; i < 2048; i += 256) dst[i] = src[i];
    __syncthreads();
    for (int ss = w; ss < 8; ss += 4) {
      const float* row = s.a.ctx[ss];
      float acc = 0.f;
#pragma unroll
      for (int i = 0; i < 16; ++i) acc += row[lane + 64 * i] * inpr[i];
#pragma unroll
      for (int off = 32; off; off >>= 1) acc += __shfl_down(acc, off, 64);
      if (lane == 0) {
        float mk = p.mask[b * 512 + ch * 128 + st * 8 + ss];
        s.a.sc[ss] = acc - (1.f - mk) * 100000.f;
      }
    }
    __syncthreads();
    float mloc = m;
#pragma unroll
    for (int ss = 0; ss < 8; ++ss) mloc = fmaxf(mloc, s.a.sc[ss]);
    float r = __expf(m - mloc);
    l *= r;
#pragma unroll
    for (int i = 0; i < 4; ++i) pwv[i] *= r;
    float e[8];
#pragma unroll
    for (int ss = 0; ss < 8; ++ss) { e[ss] = __expf(s.a.sc[ss] - mloc); l += e[ss]; }
#pragma unroll
    for (int i = 0; i < 4; ++i) {
      int d = tid + 256 * i;
      float a2 = 0.f;
#pragma unroll
      for (int ss = 0; ss < 8; ++ss) a2 += e[ss] * s.a.ctx[ss][d];
      pwv[i] += a2;
    }
    m = mloc;
  }
  int part = b * 4 + ch;
  if (tid == 0) { p.pm[part] = m; p.pl[part] = l; }
#pragma unroll
  for (int i = 0; i < 4; ++i) p.pw[(size_t)part * 1024 + tid + 256 * i] = pwv[i];
}

__device__ void phase5(const Params& p, int bid, int tid, Smem& s) {
  const int nt = bid >> 4, kc = bid & 15, n0 = nt * 64;
  if (kc < 8) {
    if (tid < 64) {
      int b = tid;
      float m0 = p.pm[b * 4], m1 = p.pm[b * 4 + 1], m2 = p.pm[b * 4 + 2], m3 = p.pm[b * 4 + 3];
      float M = fmaxf(fmaxf(m0, m1), fmaxf(m2, m3));
      float w0 = __expf(m0 - M), w1 = __expf(m1 - M), w2 = __expf(m2 - M), w3 = __expf(m3 - M);
      float inv = 1.f / (w0 * p.pl[b * 4] + w1 * p.pl[b * 4 + 1] +
                         w2 * p.pl[b * 4 + 2] + w3 * p.pl[b * 4 + 3]);
      s.o.wc[b][0] = w0 * inv; s.o.wc[b][1] = w1 * inv;
      s.o.wc[b][2] = w2 * inv; s.o.wc[b][3] = w3 * inv;
    }
    __syncthreads();
    for (int e = tid; e < 8192; e += 256) {
      int b = e >> 7, d = e & 127, col = kc * 128 + d;
      float v = s.o.wc[b][0] * p.pw[(size_t)(b * 4 + 0) * 1024 + col] +
                s.o.wc[b][1] * p.pw[(size_t)(b * 4 + 1) * 1024 + col] +
                s.o.wc[b][2] * p.pw[(size_t)(b * 4 + 2) * 1024 + col] +
                s.o.wc[b][3] * p.pw[(size_t)(b * 4 + 3) * 1024 + col];
      s.o.A[b][d] = v;
    }
  } else {
    for (int e = tid; e < 8192; e += 256) {
      int b = e >> 7, d = e & 127;
      s.o.A[b][d] = p.inpR[(size_t)b * 1024 + (kc - 8) * 128 + d];
    }
  }
  __syncthreads();
  gemm_o(p.Wout, 2048, kc * 128, p.outP + (size_t)kc * 65536, 1024, n0, s);
}

__device__ void phase6(const Params& p, int bid, int tid, int t) {
  int idx = bid * 256 + tid;
  float v = 0.f;
#pragma unroll
  for (int q = 0; q < 16; ++q) v += p.outP[(size_t)q * 65536 + idx];
  float ht = tanhf(v);
  int b = idx >> 10, j = idx & 1023;
  p.out[((size_t)b * STEPS + t) * 1024 + j] = ht;
  p.h[idx] = ht;
  if (t == STEPS - 1) {
    p.out[(size_t)4194304 + idx] = ht;
    p.out[(size_t)4194304 + 65536 + idx] = p.c[idx];
  }
}

__global__ __launch_bounds__(256, 1) void fused_k(Params p) {
  __shared__ Smem s;
  cg::grid_group grid = cg::this_grid();
  const int bid = blockIdx.x, tid = threadIdx.x;
  phase0(p, bid, tid);
  grid.sync();
  for (int t = 0; t < STEPS; ++t) {
    phase1(p, bid, tid, s); grid.sync();
    phase2(p, bid, tid);    grid.sync();
    phase3(p, bid, tid, s); grid.sync();
    phase4(p, bid, tid, s); grid.sync();
    phase5(p, bid, tid, s); grid.sync();
    phase6(p, bid, tid, t); grid.sync();
  }
}

// ---- fallback: same phases as discrete kernels ----
__global__ __launch_bounds__(256) void p0_k(Params p) { phase0(p, blockIdx.x, threadIdx.x); }
__global__ __launch_bounds__(256) void p1_k(Params p) { __shared__ Smem s; phase1(p, blockIdx.x, threadIdx.x, s); }
__global__ __launch_bounds__(256) void p2_k(Params p) { phase2(p, blockIdx.x, threadIdx.x); }
__global__ __launch_bounds__(256) void p3_k(Params p) { __shared__ Smem s; phase3(p, blockIdx.x, threadIdx.x, s); }
__global__ __launch_bounds__(256) void p4_k(Params p) { __shared__ Smem s; phase4(p, blockIdx.x, threadIdx.x, s); }
__global__ __launch_bounds__(256) void p5_k(Params p) { __shared__ Smem s; phase5(p, blockIdx.x, threadIdx.x, s); }
__global__ __launch_bounds__(256) void p6_k(Params p, int t) { phase6(p, blockIdx.x, threadIdx.x, t); }

extern "C" void kernel_launch(void* const* d_in, const int* in_sizes, int n_in,
                              void* d_out, int out_size, void* d_ws, size_t ws_size,
                              hipStream_t stream) {
  Params prm;
  prm.hx   = (const float*)d_in[0];
  prm.cx   = (const float*)d_in[1];
  prm.ctx  = (const float*)d_in[2];
  prm.mask = (const float*)d_in[3];
  prm.Wh   = (const float*)d_in[4];
  prm.bh   = (const float*)d_in[5];
  prm.Win  = (const float*)d_in[6];
  prm.Wout = (const float*)d_in[7];
  prm.out  = (float*)d_out;

  float* ws = (float*)d_ws;
  prm.h      = ws; ws += 65536;
  prm.c      = ws; ws += 65536;
  prm.hy     = ws; ws += 65536;
  prm.gatesP = ws; ws += 4 * 262144;
  prm.inpP   = ws; ws += 16 * 65536;
  prm.inpR   = ws; ws += 65536;
  prm.pm     = ws; ws += 256;
  prm.pl     = ws; ws += 256;
  prm.pw     = ws; ws += 262144;
  prm.outP   = ws; ws += 16 * 65536;

  void* args[] = { &prm };
  hipError_t err = hipLaunchCooperativeKernel((const void*)fused_k, dim3(256), dim3(256),
                                              args, 0, stream);
  if (err != hipSuccess) {
    (void)hipGetLastError();  // clear sticky error, take discrete-kernel path
    p0_k<<<256, 256, 0, stream>>>(prm);
    for (int t = 0; t < STEPS; ++t) {
      p1_k<<<256, 256, 0, stream>>>(prm);
      p2_k<<<256, 256, 0, stream>>>(prm);
      p3_k<<<256, 256, 0, stream>>>(prm);
      p4_k<<<256, 256, 0, stream>>>(prm);
      p5_k<<<256, 256, 0, stream>>>(prm);
      p6_k<<<256, 256, 0, stream>>>(prm, t);
    }
  }
}

// Round 4
// 14406.998 us; speedup vs baseline: 1.3330x; 1.3330x over previous
//
#include <hip/hip_runtime.h>
#include <hip/hip_bf16.h>

// LSTM + dot-attention recurrence, B=64, S=512, D_IN=D_HID=1024, STEPS=64.
// Round 3: persistent kernel + custom tree barrier + per-access coherent
// (agent-scope sc1) loads/stores for all cross-block ws data. Attention and
// GEMM staging use register-prefetch pipelining so HBM/L3 latency hides
// under compute (round-2 diagnosis: ctx stream was latency-bound at 518GB/s;
// cg::grid.sync cost ~30us each).

#define STEPS 64
#define NBAR  (1 + STEPS * 6)

struct Params {
  const float *hx, *cx, *ctx, *mask, *Wh, *bh, *Win, *Wout;
  float *out;
  float *h, *c, *hy, *gatesP, *inpP, *inpR, *pm, *pl, *pw, *outP;
  int *barLeaf, *barRoot, *barDone;
};

union __align__(16) Smem {
  struct { float As[64][20]; float Bs[64][20]; } g;                   // 10.0 KB
  struct { float inp[1024]; float ctx[8][1024]; float sc[8]; } a;     // 36.9 KB
  struct { float A[64][132]; float Bs[64][20]; float wc[64][4]; } o;  // 39.9 KB
};

__device__ __forceinline__ float sigmf(float x) { return 1.f / (1.f + __expf(-x)); }

// ---- coherent (device-scope, sc1) access helpers: cross-XCD safe ----
__device__ __forceinline__ float cldf(const float* p) {
  return __hip_atomic_load((float*)p, __ATOMIC_RELAXED, __HIP_MEMORY_SCOPE_AGENT);
}
__device__ __forceinline__ void cstf(float* p, float v) {
  __hip_atomic_store(p, v, __ATOMIC_RELAXED, __HIP_MEMORY_SCOPE_AGENT);
}
__device__ __forceinline__ void cst2(float* p, float a, float b) {
  float2 v = make_float2(a, b);
  __hip_atomic_store((unsigned long long*)p, *(unsigned long long*)&v,
                     __ATOMIC_RELAXED, __HIP_MEMORY_SCOPE_AGENT);
}

// ---- two-level tree barrier (256 blocks: 16 leaves x 16, then root x 16) ----
__device__ __forceinline__ void gridbar(const Params& p, int k, int bid) {
  __syncthreads();
  if (threadIdx.x == 0) {
    int* lf = p.barLeaf + (size_t)k * 256 + (size_t)(bid & 15) * 16;
    int a = __hip_atomic_fetch_add(lf, 1, __ATOMIC_ACQ_REL, __HIP_MEMORY_SCOPE_AGENT);
    if (a == 15) {
      int r = __hip_atomic_fetch_add(p.barRoot + (size_t)k * 16, 1,
                                     __ATOMIC_ACQ_REL, __HIP_MEMORY_SCOPE_AGENT);
      if (r == 15)
        __hip_atomic_store(p.barDone + (size_t)k * 16, 1,
                           __ATOMIC_RELEASE, __HIP_MEMORY_SCOPE_AGENT);
    }
    while (__hip_atomic_load(p.barDone + (size_t)k * 16,
                             __ATOMIC_ACQUIRE, __HIP_MEMORY_SCOPE_AGENT) == 0)
      __builtin_amdgcn_s_sleep(8);
  }
  __syncthreads();
}

// C[64, n0:n0+64] += A[64, kbeg:kend] @ Bm[n0:n0+64, kbeg:kend]^T
// A via coherent loads if cohA; staging reg-pipelined one k-tile ahead.
__device__ void gemm_g(const float* __restrict__ A, int lda, bool cohA,
                       const float* __restrict__ Bm, int ldb,
                       float* __restrict__ Cp, int N, int n0,
                       int kbeg, int kend, Smem& s) {
  const int tid = threadIdx.x;
  const int tx = tid & 15, ty = tid >> 4;
  float acc[4][4] = {};
  float ar[4], br[4];
#pragma unroll
  for (int q = 0; q < 4; ++q) {
    const float* ap = &A[(size_t)(q * 16 + ty) * lda + kbeg + tx];
    ar[q] = cohA ? cldf(ap) : *ap;
    br[q] = Bm[(size_t)(n0 + q * 16 + ty) * ldb + kbeg + tx];
  }
  for (int k0 = kbeg; k0 < kend; k0 += 16) {
    __syncthreads();
#pragma unroll
    for (int q = 0; q < 4; ++q) {
      s.g.As[q * 16 + ty][tx] = ar[q];
      s.g.Bs[q * 16 + ty][tx] = br[q];
    }
    if (k0 + 16 < kend) {
#pragma unroll
      for (int q = 0; q < 4; ++q) {
        const float* ap = &A[(size_t)(q * 16 + ty) * lda + k0 + 16 + tx];
        ar[q] = cohA ? cldf(ap) : *ap;
        br[q] = Bm[(size_t)(n0 + q * 16 + ty) * ldb + k0 + 16 + tx];
      }
    }
    __syncthreads();
#pragma unroll
    for (int kk = 0; kk < 16; kk += 4) {
      float4 av[4], bv[4];
#pragma unroll
      for (int i = 0; i < 4; ++i) av[i] = *(const float4*)&s.g.As[ty * 4 + i][kk];
#pragma unroll
      for (int j = 0; j < 4; ++j) bv[j] = *(const float4*)&s.g.Bs[tx * 4 + j][kk];
#pragma unroll
      for (int i = 0; i < 4; ++i)
#pragma unroll
        for (int j = 0; j < 4; ++j)
          acc[i][j] += av[i].x * bv[j].x + av[i].y * bv[j].y +
                       av[i].z * bv[j].z + av[i].w * bv[j].w;
    }
  }
#pragma unroll
  for (int i = 0; i < 4; ++i) {
    size_t row = (size_t)(ty * 4 + i) * N + n0 + tx * 4;
    cst2(&Cp[row], acc[i][0], acc[i][1]);
    cst2(&Cp[row + 2], acc[i][2], acc[i][3]);
  }
}

// C[64, n0:n0+64] = s.o.A[64, 0:128] @ Bm[n0:n0+64, kg:kg+128]^T (B pipelined)
__device__ void gemm_o(const float* __restrict__ Bm, int ldb, int kgbeg,
                       float* __restrict__ Cp, int N, int n0, Smem& s) {
  const int tid = threadIdx.x;
  const int tx = tid & 15, ty = tid >> 4;
  float acc[4][4] = {};
  float br[4];
#pragma unroll
  for (int q = 0; q < 4; ++q)
    br[q] = Bm[(size_t)(n0 + q * 16 + ty) * ldb + kgbeg + tx];
  for (int k0 = 0; k0 < 128; k0 += 16) {
    __syncthreads();
#pragma unroll
    for (int q = 0; q < 4; ++q) s.o.Bs[q * 16 + ty][tx] = br[q];
    if (k0 + 16 < 128) {
#pragma unroll
      for (int q = 0; q < 4; ++q)
        br[q] = Bm[(size_t)(n0 + q * 16 + ty) * ldb + kgbeg + k0 + 16 + tx];
    }
    __syncthreads();
#pragma unroll
    for (int kk = 0; kk < 16; kk += 4) {
      float4 av[4], bv[4];
#pragma unroll
      for (int i = 0; i < 4; ++i) av[i] = *(const float4*)&s.o.A[ty * 4 + i][k0 + kk];
#pragma unroll
      for (int j = 0; j < 4; ++j) bv[j] = *(const float4*)&s.o.Bs[tx * 4 + j][kk];
#pragma unroll
      for (int i = 0; i < 4; ++i)
#pragma unroll
        for (int j = 0; j < 4; ++j)
          acc[i][j] += av[i].x * bv[j].x + av[i].y * bv[j].y +
                       av[i].z * bv[j].z + av[i].w * bv[j].w;
    }
  }
#pragma unroll
  for (int i = 0; i < 4; ++i) {
    size_t row = (size_t)(ty * 4 + i) * N + n0 + tx * 4;
    cst2(&Cp[row], acc[i][0], acc[i][1]);
    cst2(&Cp[row + 2], acc[i][2], acc[i][3]);
  }
}

__device__ void phase0(const Params& p, int bid, int tid) {
  int idx = bid * 256 + tid;
  cstf(&p.h[idx], p.hx[idx]);
  p.c[idx] = p.cx[idx];  // c is block-private across phases (same idx map)
}

__device__ void phase1(const Params& p, int bid, int tid, Smem& s) {
  int nt = bid >> 2, kc = bid & 3;
  gemm_g(p.h, 1024, true, p.Wh, 1024, p.gatesP + (size_t)kc * 262144, 4096,
         nt * 64, kc * 256, kc * 256 + 256, s);
}

__device__ void phase2(const Params& p, int bid, int tid) {
  int idx = bid * 256 + tid;
  int b = idx >> 10, j = idx & 1023;
  float gi = p.bh[j], gf = p.bh[1024 + j], gg = p.bh[2048 + j], go = p.bh[3072 + j];
#pragma unroll
  for (int q = 0; q < 4; ++q) {
    const float* gp = p.gatesP + (size_t)q * 262144 + (size_t)b * 4096;
    gi += cldf(&gp[j]); gf += cldf(&gp[1024 + j]);
    gg += cldf(&gp[2048 + j]); go += cldf(&gp[3072 + j]);
  }
  float cy = sigmf(gf) * p.c[idx] + sigmf(gi) * tanhf(gg);
  p.c[idx] = cy;
  cstf(&p.hy[idx], sigmf(go) * tanhf(cy));
}

__device__ void phase3(const Params& p, int bid, int tid, Smem& s) {
  int nt = bid >> 4, kc = bid & 15;
  gemm_g(p.hy, 1024, true, p.Win, 1024, p.inpP + (size_t)kc * 65536, 1024,
         nt * 64, kc * 64, kc * 64 + 64, s);
}

__device__ void phase4(const Params& p, int bid, int tid, Smem& s) {
  const int b = bid >> 2, ch = bid & 3;
  const int lane = tid & 63, w = tid >> 6;
  for (int i = tid; i < 1024; i += 256) {
    float v = 0.f;
#pragma unroll
    for (int q = 0; q < 16; ++q) v += cldf(&p.inpP[(size_t)q * 65536 + (size_t)b * 1024 + i]);
    s.a.inp[i] = v;
    if (ch == 0) cstf(&p.inpR[(size_t)b * 1024 + i], v);
  }
  __syncthreads();
  float inpr[16];
#pragma unroll
  for (int i = 0; i < 16; ++i) inpr[i] = s.a.inp[lane + 64 * i];

  float m = -1e30f, l = 0.f;
  float pwv[4] = {0.f, 0.f, 0.f, 0.f};
  const float4* base = (const float4*)(p.ctx + (size_t)b * 524288 + (size_t)ch * 131072);
  float4 pf[8];
#pragma unroll
  for (int q = 0; q < 8; ++q) pf[q] = base[tid + 256 * q];
  for (int st = 0; st < 16; ++st) {
    __syncthreads();
    float4* dst = (float4*)s.a.ctx;
#pragma unroll
    for (int q = 0; q < 8; ++q) dst[tid + 256 * q] = pf[q];
    if (st < 15) {
      const float4* src = base + (size_t)(st + 1) * 2048;
#pragma unroll
      for (int q = 0; q < 8; ++q) pf[q] = src[tid + 256 * q];
    }
    __syncthreads();
    for (int ss = w; ss < 8; ss += 4) {
      const float* row = s.a.ctx[ss];
      float acc = 0.f;
#pragma unroll
      for (int i = 0; i < 16; ++i) acc += row[lane + 64 * i] * inpr[i];
#pragma unroll
      for (int off = 32; off; off >>= 1) acc += __shfl_down(acc, off, 64);
      if (lane == 0) {
        float mk = p.mask[b * 512 + ch * 128 + st * 8 + ss];
        s.a.sc[ss] = acc - (1.f - mk) * 100000.f;
      }
    }
    __syncthreads();
    float mloc = m;
#pragma unroll
    for (int ss = 0; ss < 8; ++ss) mloc = fmaxf(mloc, s.a.sc[ss]);
    float r = __expf(m - mloc);
    l *= r;
#pragma unroll
    for (int i = 0; i < 4; ++i) pwv[i] *= r;
    float e[8];
#pragma unroll
    for (int ss = 0; ss < 8; ++ss) { e[ss] = __expf(s.a.sc[ss] - mloc); l += e[ss]; }
#pragma unroll
    for (int i = 0; i < 4; ++i) {
      int d = tid + 256 * i;
      float a2 = 0.f;
#pragma unroll
      for (int ss = 0; ss < 8; ++ss) a2 += e[ss] * s.a.ctx[ss][d];
      pwv[i] += a2;
    }
    m = mloc;
  }
  int part = b * 4 + ch;
  if (tid == 0) { cstf(&p.pm[part], m); cstf(&p.pl[part], l); }
#pragma unroll
  for (int i = 0; i < 4; ++i) cstf(&p.pw[(size_t)part * 1024 + tid + 256 * i], pwv[i]);
}

__device__ void phase5(const Params& p, int bid, int tid, Smem& s) {
  const int nt = bid >> 4, kc = bid & 15, n0 = nt * 64;
  if (kc < 8) {
    if (tid < 64) {
      int b = tid;
      float m0 = cldf(&p.pm[b * 4]), m1 = cldf(&p.pm[b * 4 + 1]);
      float m2 = cldf(&p.pm[b * 4 + 2]), m3 = cldf(&p.pm[b * 4 + 3]);
      float M = fmaxf(fmaxf(m0, m1), fmaxf(m2, m3));
      float w0 = __expf(m0 - M), w1 = __expf(m1 - M), w2 = __expf(m2 - M), w3 = __expf(m3 - M);
      float inv = 1.f / (w0 * cldf(&p.pl[b * 4]) + w1 * cldf(&p.pl[b * 4 + 1]) +
                         w2 * cldf(&p.pl[b * 4 + 2]) + w3 * cldf(&p.pl[b * 4 + 3]));
      s.o.wc[b][0] = w0 * inv; s.o.wc[b][1] = w1 * inv;
      s.o.wc[b][2] = w2 * inv; s.o.wc[b][3] = w3 * inv;
    }
    __syncthreads();
    for (int e = tid; e < 8192; e += 256) {
      int b = e >> 7, d = e & 127, col = kc * 128 + d;
      float v = s.o.wc[b][0] * cldf(&p.pw[(size_t)(b * 4 + 0) * 1024 + col]) +
                s.o.wc[b][1] * cldf(&p.pw[(size_t)(b * 4 + 1) * 1024 + col]) +
                s.o.wc[b][2] * cldf(&p.pw[(size_t)(b * 4 + 2) * 1024 + col]) +
                s.o.wc[b][3] * cldf(&p.pw[(size_t)(b * 4 + 3) * 1024 + col]);
      s.o.A[b][d] = v;
    }
  } else {
    for (int e = tid; e < 8192; e += 256) {
      int b = e >> 7, d = e & 127;
      s.o.A[b][d] = cldf(&p.inpR[(size_t)b * 1024 + (kc - 8) * 128 + d]);
    }
  }
  __syncthreads();
  gemm_o(p.Wout, 2048, kc * 128, p.outP + (size_t)kc * 65536, 1024, n0, s);
}

__device__ void phase6(const Params& p, int bid, int tid, int t) {
  int idx = bid * 256 + tid;
  float v = 0.f;
#pragma unroll
  for (int q = 0; q < 16; ++q) v += cldf(&p.outP[(size_t)q * 65536 + idx]);
  float ht = tanhf(v);
  int b = idx >> 10, j = idx & 1023;
  p.out[((size_t)b * STEPS + t) * 1024 + j] = ht;
  cstf(&p.h[idx], ht);
  if (t == STEPS - 1) {
    p.out[(size_t)4194304 + idx] = ht;
    p.out[(size_t)4194304 + 65536 + idx] = p.c[idx];
  }
}

__global__ __launch_bounds__(256, 1) void fused_k(Params p) {
  __shared__ Smem s;
  const int bid = blockIdx.x, tid = threadIdx.x;
  int k = 0;
  phase0(p, bid, tid);
  gridbar(p, k++, bid);
  for (int t = 0; t < STEPS; ++t) {
    phase1(p, bid, tid, s); gridbar(p, k++, bid);
    phase2(p, bid, tid);    gridbar(p, k++, bid);
    phase3(p, bid, tid, s); gridbar(p, k++, bid);
    phase4(p, bid, tid, s); gridbar(p, k++, bid);
    phase5(p, bid, tid, s); gridbar(p, k++, bid);
    phase6(p, bid, tid, t); gridbar(p, k++, bid);
  }
}

// ---- fallback: same phases as discrete kernels ----
__global__ __launch_bounds__(256) void p0_k(Params p) { phase0(p, blockIdx.x, threadIdx.x); }
__global__ __launch_bounds__(256) void p1_k(Params p) { __shared__ Smem s; phase1(p, blockIdx.x, threadIdx.x, s); }
__global__ __launch_bounds__(256) void p2_k(Params p) { phase2(p, blockIdx.x, threadIdx.x); }
__global__ __launch_bounds__(256) void p3_k(Params p) { __shared__ Smem s; phase3(p, blockIdx.x, threadIdx.x, s); }
__global__ __launch_bounds__(256) void p4_k(Params p) { __shared__ Smem s; phase4(p, blockIdx.x, threadIdx.x, s); }
__global__ __launch_bounds__(256) void p5_k(Params p) { __shared__ Smem s; phase5(p, blockIdx.x, threadIdx.x, s); }
__global__ __launch_bounds__(256) void p6_k(Params p, int t) { phase6(p, blockIdx.x, threadIdx.x, t); }

extern "C" void kernel_launch(void* const* d_in, const int* in_sizes, int n_in,
                              void* d_out, int out_size, void* d_ws, size_t ws_size,
                              hipStream_t stream) {
  Params prm;
  prm.hx   = (const float*)d_in[0];
  prm.cx   = (const float*)d_in[1];
  prm.ctx  = (const float*)d_in[2];
  prm.mask = (const float*)d_in[3];
  prm.Wh   = (const float*)d_in[4];
  prm.bh   = (const float*)d_in[5];
  prm.Win  = (const float*)d_in[6];
  prm.Wout = (const float*)d_in[7];
  prm.out  = (float*)d_out;

  float* ws = (float*)d_ws;
  prm.h      = ws; ws += 65536;
  prm.c      = ws; ws += 65536;
  prm.hy     = ws; ws += 65536;
  prm.gatesP = ws; ws += 4 * 262144;
  prm.inpP   = ws; ws += 16 * 65536;
  prm.inpR   = ws; ws += 65536;
  prm.pm     = ws; ws += 256;
  prm.pl     = ws; ws += 256;
  prm.pw     = ws; ws += 262144;
  prm.outP   = ws; ws += 16 * 65536;
  int* wi = (int*)ws;
  prm.barLeaf = wi;                    // NBAR * 256 ints
  prm.barRoot = wi + NBAR * 256;       // NBAR * 16 ints
  prm.barDone = wi + NBAR * 256 + NBAR * 16;  // NBAR * 16 ints

  hipMemsetAsync(prm.barLeaf, 0, (size_t)NBAR * (256 + 16 + 16) * sizeof(int), stream);

  void* args[] = { &prm };
  hipError_t err = hipLaunchCooperativeKernel((const void*)fused_k, dim3(256), dim3(256),
                                              args, 0, stream);
  if (err != hipSuccess) {
    (void)hipGetLastError();  // clear sticky error, take discrete-kernel path
    p0_k<<<256, 256, 0, stream>>>(prm);
    for (int t = 0; t < STEPS; ++t) {
      p1_k<<<256, 256, 0, stream>>>(prm);
      p2_k<<<256, 256, 0, stream>>>(prm);
      p3_k<<<256, 256, 0, stream>>>(prm);
      p4_k<<<256, 256, 0, stream>>>(prm);
      p5_k<<<256, 256, 0, stream>>>(prm);
      p6_k<<<256, 256, 0, stream>>>(prm, t);
    }
  }
}